// Round 1
// baseline (488.893 us; speedup 1.0000x reference)
//
#include <hip/hip_runtime.h>
#include <math.h>

#define IN_DIM  256
#define OUT_C   256   // N_HEADS * OUT_DIM
#define NHEADS  4

static __device__ __forceinline__ float lrelu(float x) { return x > 0.f ? x : 0.01f * x; }

// ---------------- kernel: zero int buffer ----------------
__global__ void k_zero(int* __restrict__ p, int n) {
  int i = blockIdx.x * blockDim.x + threadIdx.x;
  if (i < n) p[i] = 0;
}

// ---------------- kernel: z = h @ B, B[k][c] = W[c>>6][k][c&63] ----------------
// tile: 64 nodes x 256 cols, K-step 64. 256 threads; thread micro-tile 8x8
// rows tr*8+i (tr=tid>>5), cols tc+32*j (tc=tid&31)  -> LDS-conflict-free reads.
__global__ __launch_bounds__(256) void k_gemm(const float* __restrict__ hmat,
                                              const float* __restrict__ Wmat,
                                              float* __restrict__ z, int N) {
  __shared__ float sA[64][64];      // [row][k]   16 KB
  __shared__ float sB[64][OUT_C];   // [k][col]   64 KB
  const int tid = threadIdx.x;
  const int n0  = blockIdx.x * 64;
  const int tr  = tid >> 5;
  const int tc  = tid & 31;
  float acc[8][8] = {};

  for (int k0 = 0; k0 < IN_DIM; k0 += 64) {
    // stage A: 64x64 f32 = 1024 float4, 4 per thread
    #pragma unroll
    for (int q = 0; q < 4; ++q) {
      int fid = q * 256 + tid;
      int r   = fid >> 4;
      int kk  = (fid & 15) << 2;
      int gr  = n0 + r; if (gr >= N) gr = N - 1;
      float4 v = *reinterpret_cast<const float4*>(&hmat[(size_t)gr * IN_DIM + k0 + kk]);
      *reinterpret_cast<float4*>(&sA[r][kk]) = v;
    }
    // stage B: 64x256 f32 = 4096 float4, 16 per thread
    #pragma unroll
    for (int q = 0; q < 16; ++q) {
      int fid  = q * 256 + tid;
      int k    = fid >> 6;
      int c4   = (fid & 63) << 2;
      int head = c4 >> 6;
      int o    = c4 & 63;
      float4 v = *reinterpret_cast<const float4*>(&Wmat[head * (IN_DIM * 64) + (k0 + k) * 64 + o]);
      *reinterpret_cast<float4*>(&sB[k][c4]) = v;
    }
    __syncthreads();
    #pragma unroll 4
    for (int k = 0; k < 64; ++k) {
      float a[8], b[8];
      #pragma unroll
      for (int i = 0; i < 8; ++i) a[i] = sA[tr * 8 + i][k];
      #pragma unroll
      for (int j = 0; j < 8; ++j) b[j] = sB[k][tc + 32 * j];
      #pragma unroll
      for (int i = 0; i < 8; ++i)
        #pragma unroll
        for (int j = 0; j < 8; ++j)
          acc[i][j] = fmaf(a[i], b[j], acc[i][j]);
    }
    __syncthreads();
  }
  #pragma unroll
  for (int i = 0; i < 8; ++i) {
    int gr = n0 + tr * 8 + i;
    if (gr < N) {
      #pragma unroll
      for (int j = 0; j < 8; ++j)
        z[(size_t)gr * OUT_C + tc + 32 * j] = acc[i][j];
    }
  }
}

// ---------------- kernel: e_src/e_dst per node (block=node, wave=head) ----------------
__global__ __launch_bounds__(256) void k_att(const float* __restrict__ z,
                                             const float* __restrict__ av_src,
                                             const float* __restrict__ av_dst,
                                             float* __restrict__ es_out,
                                             float* __restrict__ ed_out, int N) {
  int n   = blockIdx.x;
  int tid = threadIdx.x;
  float zv = z[(size_t)n * OUT_C + tid];
  float ps = zv * av_src[tid];
  float pd = zv * av_dst[tid];
  #pragma unroll
  for (int s = 1; s < 64; s <<= 1) {
    ps += __shfl_xor(ps, s);
    pd += __shfl_xor(pd, s);
  }
  if ((tid & 63) == 0) {
    int hh = tid >> 6;
    es_out[n * NHEADS + hh] = ps;
    ed_out[n * NHEADS + hh] = pd;
  }
}

// ---------------- kernel: per-edge logits + degree counts ----------------
__global__ void k_edge(const int* __restrict__ src, const int* __restrict__ dst,
                       const float* __restrict__ es, const float* __restrict__ ed,
                       float* __restrict__ eVal, int* __restrict__ counts, int E) {
  int e = blockIdx.x * blockDim.x + threadIdx.x;
  if (e >= E) return;
  int s = src[e], d = dst[e];
  float4 a = *reinterpret_cast<const float4*>(&es[4 * s]);
  float4 b = *reinterpret_cast<const float4*>(&ed[4 * d]);
  float4 ev;
  ev.x = lrelu(a.x + b.x);
  ev.y = lrelu(a.y + b.y);
  ev.z = lrelu(a.z + b.z);
  ev.w = lrelu(a.w + b.w);
  *reinterpret_cast<float4*>(&eVal[4 * e]) = ev;
  atomicAdd(&counts[d], 1);
}

// ---------------- kernel: exclusive scan of counts -> offsets (+cursor copy) ----------------
__global__ __launch_bounds__(1024) void k_scan(const int* __restrict__ counts,
                                               int* __restrict__ offsets,
                                               int* __restrict__ cursor, int N) {
  __shared__ int tsum[1024];
  int tid   = threadIdx.x;
  int chunk = (N + 1023) >> 10;
  int base  = tid * chunk;
  int lim   = min(N, base + chunk);
  int local = 0;
  for (int i = base; i < lim; ++i) local += counts[i];
  tsum[tid] = local;
  __syncthreads();
  for (int off = 1; off < 1024; off <<= 1) {
    int v = (tid >= off) ? tsum[tid - off] : 0;
    __syncthreads();
    tsum[tid] += v;
    __syncthreads();
  }
  int run = tsum[tid] - local;   // exclusive prefix
  for (int i = base; i < lim; ++i) {
    offsets[i] = run;
    cursor[i]  = run;
    run += counts[i];
  }
  if (tid == 1023) offsets[N] = tsum[1023];
}

// ---------------- kernel: scatter edge ids into CSR ----------------
__global__ void k_scatter(const int* __restrict__ dst, int* __restrict__ cursor,
                          int* __restrict__ edge_idx, int E) {
  int e = blockIdx.x * blockDim.x + threadIdx.x;
  if (e >= E) return;
  int pos = atomicAdd(&cursor[dst[e]], 1);
  edge_idx[pos] = e;
}

// ---------------- kernel: per-node softmax + weighted aggregation ----------------
// 1 wave per node. lane owns output channel (h*64 + lane) for h=0..3.
__global__ __launch_bounds__(64) void k_aggregate(const int* __restrict__ offsets,
                                                  const int* __restrict__ edge_idx,
                                                  const int* __restrict__ src,
                                                  const float* __restrict__ eVal,
                                                  const float* __restrict__ z,
                                                  float* __restrict__ out, int N) {
  __shared__ float pb[NHEADS][64];
  __shared__ int   se[64];
  int n    = blockIdx.x;
  int lane = threadIdx.x;
  int beg  = offsets[n], end = offsets[n + 1];
  float acc0 = 0.f, acc1 = 0.f, acc2 = 0.f, acc3 = 0.f;

  if (end > beg) {
    // pass A: per-head max over incoming edges
    float m0 = -1e30f, m1 = -1e30f, m2 = -1e30f, m3 = -1e30f;
    for (int i = beg + lane; i < end; i += 64) {
      float4 e4 = *reinterpret_cast<const float4*>(&eVal[4 * edge_idx[i]]);
      m0 = fmaxf(m0, e4.x); m1 = fmaxf(m1, e4.y);
      m2 = fmaxf(m2, e4.z); m3 = fmaxf(m3, e4.w);
    }
    #pragma unroll
    for (int s = 1; s < 64; s <<= 1) {
      m0 = fmaxf(m0, __shfl_xor(m0, s));
      m1 = fmaxf(m1, __shfl_xor(m1, s));
      m2 = fmaxf(m2, __shfl_xor(m2, s));
      m3 = fmaxf(m3, __shfl_xor(m3, s));
    }
    // pass B: p = exp(e - m); accumulate p*z and p (denominator folded in)
    float d0 = 0.f, d1 = 0.f, d2 = 0.f, d3 = 0.f;
    for (int cb = beg; cb < end; cb += 64) {
      int cnt = min(64, end - cb);
      if (lane < cnt) {
        int eid = edge_idx[cb + lane];
        float4 e4 = *reinterpret_cast<const float4*>(&eVal[4 * eid]);
        float p0 = __expf(e4.x - m0);
        float p1 = __expf(e4.y - m1);
        float p2 = __expf(e4.z - m2);
        float p3 = __expf(e4.w - m3);
        pb[0][lane] = p0; pb[1][lane] = p1; pb[2][lane] = p2; pb[3][lane] = p3;
        se[lane] = src[eid];
        d0 += p0; d1 += p1; d2 += p2; d3 += p3;
      }
      __syncthreads();
      for (int t = 0; t < cnt; ++t) {
        const float* zr = z + (size_t)se[t] * OUT_C;
        float p0 = pb[0][t], p1 = pb[1][t], p2 = pb[2][t], p3 = pb[3][t];
        acc0 = fmaf(p0, zr[lane],       acc0);
        acc1 = fmaf(p1, zr[64 + lane],  acc1);
        acc2 = fmaf(p2, zr[128 + lane], acc2);
        acc3 = fmaf(p3, zr[192 + lane], acc3);
      }
      __syncthreads();
    }
    #pragma unroll
    for (int s = 1; s < 64; s <<= 1) {
      d0 += __shfl_xor(d0, s);
      d1 += __shfl_xor(d1, s);
      d2 += __shfl_xor(d2, s);
      d3 += __shfl_xor(d3, s);
    }
    acc0 *= (1.f / d0); acc1 *= (1.f / d1); acc2 *= (1.f / d2); acc3 *= (1.f / d3);
  }
  float* orow = out + (size_t)n * OUT_C;
  orow[lane]        = acc0;
  orow[64 + lane]   = acc1;
  orow[128 + lane]  = acc2;
  orow[192 + lane]  = acc3;
}

extern "C" void kernel_launch(void* const* d_in, const int* in_sizes, int n_in,
                              void* d_out, int out_size, void* d_ws, size_t ws_size,
                              hipStream_t stream) {
  const float* hmat  = (const float*)d_in[0];
  const int*   src   = (const int*)d_in[1];
  const int*   dst   = (const int*)d_in[2];
  const float* Wmat  = (const float*)d_in[3];
  const float* avsrc = (const float*)d_in[4];
  const float* avdst = (const float*)d_in[5];
  float* out = (float*)d_out;
  const int N = in_sizes[0] / IN_DIM;
  const int E = in_sizes[1];

  char* ws = (char*)d_ws;
  size_t off = 0;
  auto alloc = [&](size_t bytes) -> void* {
    void* p = ws + off;
    off = (off + bytes + 255) & ~(size_t)255;
    return p;
  };
  float* z        = (float*)alloc((size_t)N * OUT_C * sizeof(float));   // 51.2 MB
  float* es       = (float*)alloc((size_t)N * NHEADS * sizeof(float));
  float* ed       = (float*)alloc((size_t)N * NHEADS * sizeof(float));
  float* eVal     = (float*)alloc((size_t)E * NHEADS * sizeof(float));  // 12.8 MB
  int*   counts   = (int*)alloc((size_t)N * sizeof(int));
  int*   offsets  = (int*)alloc((size_t)(N + 1) * sizeof(int));
  int*   cursor   = (int*)alloc((size_t)N * sizeof(int));
  int*   edge_idx = (int*)alloc((size_t)E * sizeof(int));               // 3.2 MB

  hipLaunchKernelGGL(k_zero, dim3((N + 255) / 256), dim3(256), 0, stream, counts, N);
  hipLaunchKernelGGL(k_gemm, dim3((N + 63) / 64), dim3(256), 0, stream, hmat, Wmat, z, N);
  hipLaunchKernelGGL(k_att, dim3(N), dim3(256), 0, stream, z, avsrc, avdst, es, ed, N);
  hipLaunchKernelGGL(k_edge, dim3((E + 255) / 256), dim3(256), 0, stream,
                     src, dst, es, ed, eVal, counts, E);
  hipLaunchKernelGGL(k_scan, dim3(1), dim3(1024), 0, stream, counts, offsets, cursor, N);
  hipLaunchKernelGGL(k_scatter, dim3((E + 255) / 256), dim3(256), 0, stream,
                     dst, cursor, edge_idx, E);
  hipLaunchKernelGGL(k_aggregate, dim3(N), dim3(64), 0, stream,
                     offsets, edge_idx, src, eVal, z, out, N);
}

// Round 2
// 335.279 us; speedup vs baseline: 1.4582x; 1.4582x over previous
//
#include <hip/hip_runtime.h>
#include <math.h>

#define IN_DIM  256
#define OUT_C   256   // N_HEADS * OUT_DIM
#define NHEADS  4

typedef __attribute__((ext_vector_type(8))) short short8;
typedef __attribute__((ext_vector_type(4))) float f32x4;

static __device__ __forceinline__ float lrelu(float x) { return x > 0.f ? x : 0.01f * x; }

// round-to-nearest-even f32 -> bf16 bits
static __device__ __forceinline__ ushort f2bf(float f) {
  uint u = __float_as_uint(f);
  uint r = (u + 0x7fffu + ((u >> 16) & 1u)) >> 16;
  return (ushort)r;
}
static __device__ __forceinline__ float bflo(uint v) { return __uint_as_float(v << 16); }
static __device__ __forceinline__ float bfhi(uint v) { return __uint_as_float(v & 0xffff0000u); }

// ---------------- zero int buffer ----------------
__global__ void k_zero(int* __restrict__ p, int n) {
  int i = blockIdx.x * blockDim.x + threadIdx.x;
  if (i < n) p[i] = 0;
}

// ---------------- cast h (f32) -> hb (bf16) ----------------
__global__ __launch_bounds__(256) void k_cast_h(const float* __restrict__ h,
                                                ushort* __restrict__ hb, int n4) {
  int stride = gridDim.x * blockDim.x;
  for (int i = blockIdx.x * blockDim.x + threadIdx.x; i < n4; i += stride) {
    float4 v = reinterpret_cast<const float4*>(h)[i];
    uint2 o;
    o.x = (uint)f2bf(v.x) | ((uint)f2bf(v.y) << 16);
    o.y = (uint)f2bf(v.z) | ((uint)f2bf(v.w) << 16);
    reinterpret_cast<uint2*>(hb)[i] = o;
  }
}

// ---------------- W [4][256][64] f32 -> BT [256 cols][256 k] bf16 ----------------
__global__ __launch_bounds__(256) void k_prep_w(const float* __restrict__ W,
                                                ushort* __restrict__ BT) {
  int t = blockIdx.x * 256 + threadIdx.x;          // 65536 total
  int hh = t >> 14, k = (t >> 6) & 255, o = t & 63;
  BT[(hh * 64 + o) * 256 + k] = f2bf(W[t]);
}

// ---------------- MFMA GEMM: zb = bf16( hb @ B ), fused e_src/e_dst epilogue ----
// tile 64 rows x 256 cols, 4 waves; wave w owns cols [w*64, w*64+64).
__global__ __launch_bounds__(256) void k_gemm_mfma(const ushort* __restrict__ hb,
                                                   const ushort* __restrict__ BT,
                                                   const float* __restrict__ avsrc,
                                                   const float* __restrict__ avdst,
                                                   ushort* __restrict__ zb,
                                                   float* __restrict__ es,
                                                   float* __restrict__ ed, int N) {
  __shared__ ushort sA[64 * 32];    // [row][k]  4 KB
  __shared__ ushort sB[256 * 32];   // [col][k] 16 KB
  const int tid = threadIdx.x;
  const int w   = tid >> 6;
  const int l   = tid & 63;
  const int n0  = blockIdx.x * 64;
  const int l15 = l & 15;
  const int lg  = l >> 4;           // 16-lane group id
  f32x4 acc[4][4] = {};

  for (int k0 = 0; k0 < IN_DIM; k0 += 32) {
    // stage A: 64x32 bf16 = 4KB, one uint4 per thread
    {
      int row = tid >> 2, ko = (tid & 3) * 8;
      int gr = n0 + row; if (gr >= N) gr = N - 1;
      uint4 v = *reinterpret_cast<const uint4*>(hb + (size_t)gr * IN_DIM + k0 + ko);
      *reinterpret_cast<uint4*>(sA + row * 32 + ko) = v;
    }
    // stage B: 256x32 bf16 = 16KB, 4 uint4 per thread
    #pragma unroll
    for (int q = 0; q < 4; ++q) {
      int fid = q * 256 + tid;
      int col = fid >> 2, ko = (fid & 3) * 8;
      uint4 v = *reinterpret_cast<const uint4*>(BT + (size_t)col * 256 + k0 + ko);
      *reinterpret_cast<uint4*>(sB + col * 32 + ko) = v;
    }
    __syncthreads();
    const int ksel = lg * 8;
    short8 a[4], b[4];
    #pragma unroll
    for (int m = 0; m < 4; ++m)
      a[m] = *reinterpret_cast<const short8*>(sA + (m * 16 + l15) * 32 + ksel);
    #pragma unroll
    for (int cf = 0; cf < 4; ++cf)
      b[cf] = *reinterpret_cast<const short8*>(sB + (w * 64 + cf * 16 + l15) * 32 + ksel);
    #pragma unroll
    for (int m = 0; m < 4; ++m)
      #pragma unroll
      for (int cf = 0; cf < 4; ++cf)
        acc[m][cf] = __builtin_amdgcn_mfma_f32_16x16x32_bf16(a[m], b[cf], acc[m][cf], 0, 0, 0);
    __syncthreads();
  }

  // epilogue: z store (bf16) + fused e_src/e_dst
  float asv[4], adv[4];
  #pragma unroll
  for (int cf = 0; cf < 4; ++cf) {
    asv[cf] = avsrc[w * 64 + cf * 16 + l15];
    adv[cf] = avdst[w * 64 + cf * 16 + l15];
  }
  #pragma unroll
  for (int m = 0; m < 4; ++m) {
    #pragma unroll
    for (int r = 0; r < 4; ++r) {
      int row = m * 16 + lg * 4 + r;
      int gr  = n0 + row;
      float ss = 0.f, dd = 0.f;
      #pragma unroll
      for (int cf = 0; cf < 4; ++cf) {
        ss = fmaf(acc[m][cf][r], asv[cf], ss);
        dd = fmaf(acc[m][cf][r], adv[cf], dd);
      }
      #pragma unroll
      for (int s = 1; s < 16; s <<= 1) {
        ss += __shfl_xor(ss, s);
        dd += __shfl_xor(dd, s);
      }
      if (gr < N) {
        if (l15 == 0) { es[gr * 4 + w] = ss; ed[gr * 4 + w] = dd; }
        #pragma unroll
        for (int cf = 0; cf < 4; ++cf)
          zb[(size_t)gr * OUT_C + w * 64 + cf * 16 + l15] = f2bf(acc[m][cf][r]);
      }
    }
  }
}

// ---------------- per-edge logits + degree counts ----------------
__global__ void k_edge(const int* __restrict__ src, const int* __restrict__ dst,
                       const float* __restrict__ es, const float* __restrict__ ed,
                       float* __restrict__ eVal, int* __restrict__ counts, int E) {
  int e = blockIdx.x * blockDim.x + threadIdx.x;
  if (e >= E) return;
  int s = src[e], d = dst[e];
  float4 a = *reinterpret_cast<const float4*>(&es[4 * s]);
  float4 b = *reinterpret_cast<const float4*>(&ed[4 * d]);
  float4 ev;
  ev.x = lrelu(a.x + b.x);
  ev.y = lrelu(a.y + b.y);
  ev.z = lrelu(a.z + b.z);
  ev.w = lrelu(a.w + b.w);
  *reinterpret_cast<float4*>(&eVal[4 * e]) = ev;
  atomicAdd(&counts[d], 1);
}

// ---------------- exclusive scan of counts -> offsets (+cursor copy) ----------------
__global__ __launch_bounds__(1024) void k_scan(const int* __restrict__ counts,
                                               int* __restrict__ offsets,
                                               int* __restrict__ cursor, int N) {
  __shared__ int tsum[1024];
  int tid   = threadIdx.x;
  int chunk = (N + 1023) >> 10;
  int base  = tid * chunk;
  int lim   = min(N, base + chunk);
  int local = 0;
  for (int i = base; i < lim; ++i) local += counts[i];
  tsum[tid] = local;
  __syncthreads();
  for (int off = 1; off < 1024; off <<= 1) {
    int v = (tid >= off) ? tsum[tid - off] : 0;
    __syncthreads();
    tsum[tid] += v;
    __syncthreads();
  }
  int run = tsum[tid] - local;   // exclusive prefix
  for (int i = base; i < lim; ++i) {
    offsets[i] = run;
    cursor[i]  = run;
    run += counts[i];
  }
  if (tid == 1023) offsets[N] = tsum[1023];
}

// ---------------- scatter edge ids into CSR ----------------
__global__ void k_scatter(const int* __restrict__ dst, int* __restrict__ cursor,
                          int* __restrict__ edge_idx, int E) {
  int e = blockIdx.x * blockDim.x + threadIdx.x;
  if (e >= E) return;
  int pos = atomicAdd(&cursor[dst[e]], 1);
  edge_idx[pos] = e;
}

// ---------------- per-node softmax + weighted aggregation (bf16 z gather) -----
// 1 wave per node. lane owns 4 consecutive channels [4*lane, 4*lane+4) — all in
// head (lane>>4). One uint2 (8B) z load + float4 out store per lane.
__global__ __launch_bounds__(64) void k_aggregate(const int* __restrict__ offsets,
                                                  const int* __restrict__ edge_idx,
                                                  const int* __restrict__ src,
                                                  const float* __restrict__ eVal,
                                                  const ushort* __restrict__ zb,
                                                  float* __restrict__ out, int N) {
  __shared__ float pb[64][4];
  __shared__ int   se[64];
  int n    = blockIdx.x;
  int lane = threadIdx.x;
  int hsel = lane >> 4;
  int beg  = offsets[n], end = offsets[n + 1];
  float acc0 = 0.f, acc1 = 0.f, acc2 = 0.f, acc3 = 0.f;

  if (end > beg) {
    // pass A: per-head max
    float m0 = -1e30f, m1 = -1e30f, m2 = -1e30f, m3 = -1e30f;
    for (int i = beg + lane; i < end; i += 64) {
      float4 e4 = *reinterpret_cast<const float4*>(&eVal[4 * edge_idx[i]]);
      m0 = fmaxf(m0, e4.x); m1 = fmaxf(m1, e4.y);
      m2 = fmaxf(m2, e4.z); m3 = fmaxf(m3, e4.w);
    }
    #pragma unroll
    for (int s = 1; s < 64; s <<= 1) {
      m0 = fmaxf(m0, __shfl_xor(m0, s));
      m1 = fmaxf(m1, __shfl_xor(m1, s));
      m2 = fmaxf(m2, __shfl_xor(m2, s));
      m3 = fmaxf(m3, __shfl_xor(m3, s));
    }
    // pass B: p = exp(e-m); accumulate p*z and p
    float d0 = 0.f, d1 = 0.f, d2 = 0.f, d3 = 0.f;
    for (int cb = beg; cb < end; cb += 64) {
      int cnt = min(64, end - cb);
      if (lane < cnt) {
        int eid = edge_idx[cb + lane];
        float4 e4 = *reinterpret_cast<const float4*>(&eVal[4 * eid]);
        float p0 = __expf(e4.x - m0);
        float p1 = __expf(e4.y - m1);
        float p2 = __expf(e4.z - m2);
        float p3 = __expf(e4.w - m3);
        pb[lane][0] = p0; pb[lane][1] = p1; pb[lane][2] = p2; pb[lane][3] = p3;
        se[lane] = src[eid];
        d0 += p0; d1 += p1; d2 += p2; d3 += p3;
      }
      __syncthreads();
      for (int t = 0; t < cnt; ++t) {
        float p = pb[t][hsel];
        uint2 v = reinterpret_cast<const uint2*>(zb + (size_t)se[t] * OUT_C)[lane];
        acc0 = fmaf(p, bflo(v.x), acc0);
        acc1 = fmaf(p, bfhi(v.x), acc1);
        acc2 = fmaf(p, bflo(v.y), acc2);
        acc3 = fmaf(p, bfhi(v.y), acc3);
      }
      __syncthreads();
    }
    #pragma unroll
    for (int s = 1; s < 64; s <<= 1) {
      d0 += __shfl_xor(d0, s);
      d1 += __shfl_xor(d1, s);
      d2 += __shfl_xor(d2, s);
      d3 += __shfl_xor(d3, s);
    }
    float dh = (hsel == 0) ? d0 : (hsel == 1) ? d1 : (hsel == 2) ? d2 : d3;
    float inv = 1.f / dh;
    acc0 *= inv; acc1 *= inv; acc2 *= inv; acc3 *= inv;
  }
  float4 o4 = { acc0, acc1, acc2, acc3 };
  *reinterpret_cast<float4*>(out + (size_t)n * OUT_C + 4 * lane) = o4;
}

extern "C" void kernel_launch(void* const* d_in, const int* in_sizes, int n_in,
                              void* d_out, int out_size, void* d_ws, size_t ws_size,
                              hipStream_t stream) {
  const float* hmat  = (const float*)d_in[0];
  const int*   src   = (const int*)d_in[1];
  const int*   dst   = (const int*)d_in[2];
  const float* Wmat  = (const float*)d_in[3];
  const float* avsrc = (const float*)d_in[4];
  const float* avdst = (const float*)d_in[5];
  float* out = (float*)d_out;
  const int N = in_sizes[0] / IN_DIM;
  const int E = in_sizes[1];

  char* ws = (char*)d_ws;
  size_t off = 0;
  auto alloc = [&](size_t bytes) -> void* {
    void* p = ws + off;
    off = (off + bytes + 255) & ~(size_t)255;
    return p;
  };
  ushort* hb      = (ushort*)alloc((size_t)N * IN_DIM * sizeof(ushort));   // 25.6 MB
  ushort* BT      = (ushort*)alloc((size_t)OUT_C * IN_DIM * sizeof(ushort)); // 128 KB
  ushort* zb      = (ushort*)alloc((size_t)N * OUT_C * sizeof(ushort));    // 25.6 MB
  float*  es      = (float*)alloc((size_t)N * NHEADS * sizeof(float));
  float*  ed      = (float*)alloc((size_t)N * NHEADS * sizeof(float));
  float*  eVal    = (float*)alloc((size_t)E * NHEADS * sizeof(float));     // 12.8 MB
  int*    counts  = (int*)alloc((size_t)N * sizeof(int));
  int*    offsets = (int*)alloc((size_t)(N + 1) * sizeof(int));
  int*    cursor  = (int*)alloc((size_t)N * sizeof(int));
  int*    edge_idx= (int*)alloc((size_t)E * sizeof(int));                  // 3.2 MB

  hipLaunchKernelGGL(k_zero, dim3((N + 255) / 256), dim3(256), 0, stream, counts, N);
  hipLaunchKernelGGL(k_cast_h, dim3(2048), dim3(256), 0, stream,
                     hmat, hb, N * IN_DIM / 4);
  hipLaunchKernelGGL(k_prep_w, dim3(256), dim3(256), 0, stream, Wmat, BT);
  hipLaunchKernelGGL(k_gemm_mfma, dim3((N + 63) / 64), dim3(256), 0, stream,
                     hb, BT, avsrc, avdst, zb, es, ed, N);
  hipLaunchKernelGGL(k_edge, dim3((E + 255) / 256), dim3(256), 0, stream,
                     src, dst, es, ed, eVal, counts, E);
  hipLaunchKernelGGL(k_scan, dim3(1), dim3(1024), 0, stream, counts, offsets, cursor, N);
  hipLaunchKernelGGL(k_scatter, dim3((E + 255) / 256), dim3(256), 0, stream,
                     dst, cursor, edge_idx, E);
  hipLaunchKernelGGL(k_aggregate, dim3(N), dim3(64), 0, stream,
                     offsets, edge_idx, src, eVal, zb, out, N);
}

// Round 3
// 237.498 us; speedup vs baseline: 2.0585x; 1.4117x over previous
//
#include <hip/hip_runtime.h>
#include <math.h>

#define IN_DIM  256
#define OUT_C   256   // N_HEADS * OUT_DIM
#define NHEADS  4
#define SCAN_CHUNK 2048

typedef __attribute__((ext_vector_type(8))) short short8;
typedef __attribute__((ext_vector_type(4))) float f32x4;

static __device__ __forceinline__ float lrelu(float x) { return x > 0.f ? x : 0.01f * x; }

// round-to-nearest-even f32 -> bf16 bits
static __device__ __forceinline__ ushort f2bf(float f) {
  uint u = __float_as_uint(f);
  uint r = (u + 0x7fffu + ((u >> 16) & 1u)) >> 16;
  return (ushort)r;
}
static __device__ __forceinline__ float bflo(uint v) { return __uint_as_float(v << 16); }
static __device__ __forceinline__ float bfhi(uint v) { return __uint_as_float(v & 0xffff0000u); }

// ---------------- zero int buffer ----------------
__global__ void k_zero(int* __restrict__ p, int n) {
  int i = blockIdx.x * blockDim.x + threadIdx.x;
  if (i < n) p[i] = 0;
}

// ---------------- cast h (f32) -> hb (bf16) ----------------
__global__ __launch_bounds__(256) void k_cast_h(const float* __restrict__ h,
                                                ushort* __restrict__ hb, int n4) {
  int stride = gridDim.x * blockDim.x;
  for (int i = blockIdx.x * blockDim.x + threadIdx.x; i < n4; i += stride) {
    float4 v = reinterpret_cast<const float4*>(h)[i];
    uint2 o;
    o.x = (uint)f2bf(v.x) | ((uint)f2bf(v.y) << 16);
    o.y = (uint)f2bf(v.z) | ((uint)f2bf(v.w) << 16);
    reinterpret_cast<uint2*>(hb)[i] = o;
  }
}

// ---------------- W [4][256][64] f32 -> BT [256 cols][256 k] bf16 ----------------
__global__ __launch_bounds__(256) void k_prep_w(const float* __restrict__ W,
                                                ushort* __restrict__ BT) {
  int t = blockIdx.x * 256 + threadIdx.x;          // 65536 total
  int hh = t >> 14, k = (t >> 6) & 255, o = t & 63;
  BT[(hh * 64 + o) * 256 + k] = f2bf(W[t]);
}

// ---------------- MFMA GEMM: zb = bf16( hb @ B ), fused e_src/e_dst epilogue ----
// tile 64 rows x 256 cols, 4 waves; wave w owns cols [w*64, w*64+64).
__global__ __launch_bounds__(256) void k_gemm_mfma(const ushort* __restrict__ hb,
                                                   const ushort* __restrict__ BT,
                                                   const float* __restrict__ avsrc,
                                                   const float* __restrict__ avdst,
                                                   ushort* __restrict__ zb,
                                                   float* __restrict__ es,
                                                   float* __restrict__ ed, int N) {
  __shared__ ushort sA[64 * 32];    // [row][k]  4 KB
  __shared__ ushort sB[256 * 32];   // [col][k] 16 KB
  const int tid = threadIdx.x;
  const int w   = tid >> 6;
  const int l   = tid & 63;
  const int n0  = blockIdx.x * 64;
  const int l15 = l & 15;
  const int lg  = l >> 4;           // 16-lane group id
  f32x4 acc[4][4] = {};

  for (int k0 = 0; k0 < IN_DIM; k0 += 32) {
    // stage A: 64x32 bf16 = 4KB, one uint4 per thread
    {
      int row = tid >> 2, ko = (tid & 3) * 8;
      int gr = n0 + row; if (gr >= N) gr = N - 1;
      uint4 v = *reinterpret_cast<const uint4*>(hb + (size_t)gr * IN_DIM + k0 + ko);
      *reinterpret_cast<uint4*>(sA + row * 32 + ko) = v;
    }
    // stage B: 256x32 bf16 = 16KB, 4 uint4 per thread
    #pragma unroll
    for (int q = 0; q < 4; ++q) {
      int fid = q * 256 + tid;
      int col = fid >> 2, ko = (fid & 3) * 8;
      uint4 v = *reinterpret_cast<const uint4*>(BT + (size_t)col * 256 + k0 + ko);
      *reinterpret_cast<uint4*>(sB + col * 32 + ko) = v;
    }
    __syncthreads();
    const int ksel = lg * 8;
    short8 a[4], b[4];
    #pragma unroll
    for (int m = 0; m < 4; ++m)
      a[m] = *reinterpret_cast<const short8*>(sA + (m * 16 + l15) * 32 + ksel);
    #pragma unroll
    for (int cf = 0; cf < 4; ++cf)
      b[cf] = *reinterpret_cast<const short8*>(sB + (w * 64 + cf * 16 + l15) * 32 + ksel);
    #pragma unroll
    for (int m = 0; m < 4; ++m)
      #pragma unroll
      for (int cf = 0; cf < 4; ++cf)
        acc[m][cf] = __builtin_amdgcn_mfma_f32_16x16x32_bf16(a[m], b[cf], acc[m][cf], 0, 0, 0);
    __syncthreads();
  }

  // epilogue: z store (bf16) + fused e_src/e_dst
  float asv[4], adv[4];
  #pragma unroll
  for (int cf = 0; cf < 4; ++cf) {
    asv[cf] = avsrc[w * 64 + cf * 16 + l15];
    adv[cf] = avdst[w * 64 + cf * 16 + l15];
  }
  #pragma unroll
  for (int m = 0; m < 4; ++m) {
    #pragma unroll
    for (int r = 0; r < 4; ++r) {
      int row = m * 16 + lg * 4 + r;
      int gr  = n0 + row;
      float ss = 0.f, dd = 0.f;
      #pragma unroll
      for (int cf = 0; cf < 4; ++cf) {
        ss = fmaf(acc[m][cf][r], asv[cf], ss);
        dd = fmaf(acc[m][cf][r], adv[cf], dd);
      }
      #pragma unroll
      for (int s = 1; s < 16; s <<= 1) {
        ss += __shfl_xor(ss, s);
        dd += __shfl_xor(dd, s);
      }
      if (gr < N) {
        if (l15 == 0) { es[gr * 4 + w] = ss; ed[gr * 4 + w] = dd; }
        #pragma unroll
        for (int cf = 0; cf < 4; ++cf)
          zb[(size_t)gr * OUT_C + w * 64 + cf * 16 + l15] = f2bf(acc[m][cf][r]);
      }
    }
  }
}

// ---------------- per-edge logits + degree counts ----------------
__global__ void k_edge(const int* __restrict__ src, const int* __restrict__ dst,
                       const float* __restrict__ es, const float* __restrict__ ed,
                       float* __restrict__ eVal, int* __restrict__ counts, int E) {
  int e = blockIdx.x * blockDim.x + threadIdx.x;
  if (e >= E) return;
  int s = src[e], d = dst[e];
  float4 a = *reinterpret_cast<const float4*>(&es[4 * s]);
  float4 b = *reinterpret_cast<const float4*>(&ed[4 * d]);
  float4 ev;
  ev.x = lrelu(a.x + b.x);
  ev.y = lrelu(a.y + b.y);
  ev.z = lrelu(a.z + b.z);
  ev.w = lrelu(a.w + b.w);
  *reinterpret_cast<float4*>(&eVal[4 * e]) = ev;
  atomicAdd(&counts[d], 1);
}

// ---------------- hierarchical scan, phase 1: per-block chunk sums ----------------
__global__ __launch_bounds__(256) void k_scan_part(const int* __restrict__ counts,
                                                   int* __restrict__ partials, int N) {
  __shared__ int ssum[256];
  int tid  = threadIdx.x;
  int idx  = blockIdx.x * SCAN_CHUNK + tid * 8;
  int s = 0;
  #pragma unroll
  for (int j = 0; j < 8; ++j) {
    int i = idx + j;
    if (i < N) s += counts[i];
  }
  ssum[tid] = s;
  __syncthreads();
  #pragma unroll
  for (int off = 128; off > 0; off >>= 1) {
    if (tid < off) ssum[tid] += ssum[tid + off];
    __syncthreads();
  }
  if (tid == 0) partials[blockIdx.x] = ssum[0];
}

// ---------------- phase 2: exclusive scan of partials (single block) ----------------
__global__ __launch_bounds__(256) void k_scan_top(int* __restrict__ partials, int B) {
  __shared__ int t[256];
  int tid  = threadIdx.x;
  int orig = (tid < B) ? partials[tid] : 0;
  t[tid] = orig;
  __syncthreads();
  #pragma unroll
  for (int off = 1; off < 256; off <<= 1) {
    int v = (tid >= off) ? t[tid - off] : 0;
    __syncthreads();
    t[tid] += v;
    __syncthreads();
  }
  if (tid < B) partials[tid] = t[tid] - orig;   // exclusive
}

// ---------------- phase 3: final scan: offsets + cursor ----------------
__global__ __launch_bounds__(256) void k_scan_final(const int* __restrict__ counts,
                                                    const int* __restrict__ partials,
                                                    int* __restrict__ offsets,
                                                    int* __restrict__ cursor, int N) {
  __shared__ int tsum[256];
  int tid = threadIdx.x;
  int idx = blockIdx.x * SCAN_CHUNK + tid * 8;
  int local[8];
  int s = 0;
  #pragma unroll
  for (int j = 0; j < 8; ++j) {
    int i = idx + j;
    local[j] = (i < N) ? counts[i] : 0;
    s += local[j];
  }
  tsum[tid] = s;
  __syncthreads();
  #pragma unroll
  for (int off = 1; off < 256; off <<= 1) {
    int v = (tid >= off) ? tsum[tid - off] : 0;
    __syncthreads();
    tsum[tid] += v;
    __syncthreads();
  }
  int run = tsum[tid] - s + partials[blockIdx.x];
  #pragma unroll
  for (int j = 0; j < 8; ++j) {
    int i = idx + j;
    if (i < N) {
      offsets[i] = run;
      cursor[i]  = run;
      run += local[j];
      if (i == N - 1) offsets[N] = run;
    }
  }
}

// ---------------- scatter edge ids into CSR ----------------
__global__ void k_scatter(const int* __restrict__ dst, int* __restrict__ cursor,
                          int* __restrict__ edge_idx, int E) {
  int e = blockIdx.x * blockDim.x + threadIdx.x;
  if (e >= E) return;
  int pos = atomicAdd(&cursor[dst[e]], 1);
  edge_idx[pos] = e;
}

// ---------------- per-node softmax + weighted aggregation (bf16 z gather) -----
// 1 wave per node. lane owns 4 consecutive channels [4*lane, 4*lane+4) — all in
// head (lane>>4). One uint2 (8B) z load + float4 out store per lane.
__global__ __launch_bounds__(64) void k_aggregate(const int* __restrict__ offsets,
                                                  const int* __restrict__ edge_idx,
                                                  const int* __restrict__ src,
                                                  const float* __restrict__ eVal,
                                                  const ushort* __restrict__ zb,
                                                  float* __restrict__ out, int N) {
  __shared__ float pb[64][4];
  __shared__ int   se[64];
  int n    = blockIdx.x;
  int lane = threadIdx.x;
  int hsel = lane >> 4;
  int beg  = offsets[n], end = offsets[n + 1];
  float acc0 = 0.f, acc1 = 0.f, acc2 = 0.f, acc3 = 0.f;

  if (end > beg) {
    // pass A: per-head max
    float m0 = -1e30f, m1 = -1e30f, m2 = -1e30f, m3 = -1e30f;
    for (int i = beg + lane; i < end; i += 64) {
      float4 e4 = *reinterpret_cast<const float4*>(&eVal[4 * edge_idx[i]]);
      m0 = fmaxf(m0, e4.x); m1 = fmaxf(m1, e4.y);
      m2 = fmaxf(m2, e4.z); m3 = fmaxf(m3, e4.w);
    }
    #pragma unroll
    for (int s = 1; s < 64; s <<= 1) {
      m0 = fmaxf(m0, __shfl_xor(m0, s));
      m1 = fmaxf(m1, __shfl_xor(m1, s));
      m2 = fmaxf(m2, __shfl_xor(m2, s));
      m3 = fmaxf(m3, __shfl_xor(m3, s));
    }
    // pass B: p = exp(e-m); accumulate p*z and p
    float d0 = 0.f, d1 = 0.f, d2 = 0.f, d3 = 0.f;
    for (int cb = beg; cb < end; cb += 64) {
      int cnt = min(64, end - cb);
      if (lane < cnt) {
        int eid = edge_idx[cb + lane];
        float4 e4 = *reinterpret_cast<const float4*>(&eVal[4 * eid]);
        float p0 = __expf(e4.x - m0);
        float p1 = __expf(e4.y - m1);
        float p2 = __expf(e4.z - m2);
        float p3 = __expf(e4.w - m3);
        pb[lane][0] = p0; pb[lane][1] = p1; pb[lane][2] = p2; pb[lane][3] = p3;
        se[lane] = src[eid];
        d0 += p0; d1 += p1; d2 += p2; d3 += p3;
      }
      __syncthreads();
      for (int t = 0; t < cnt; ++t) {
        float p = pb[t][hsel];
        uint2 v = reinterpret_cast<const uint2*>(zb + (size_t)se[t] * OUT_C)[lane];
        acc0 = fmaf(p, bflo(v.x), acc0);
        acc1 = fmaf(p, bfhi(v.x), acc1);
        acc2 = fmaf(p, bflo(v.y), acc2);
        acc3 = fmaf(p, bfhi(v.y), acc3);
      }
      __syncthreads();
    }
    #pragma unroll
    for (int s = 1; s < 64; s <<= 1) {
      d0 += __shfl_xor(d0, s);
      d1 += __shfl_xor(d1, s);
      d2 += __shfl_xor(d2, s);
      d3 += __shfl_xor(d3, s);
    }
    float dh = (hsel == 0) ? d0 : (hsel == 1) ? d1 : (hsel == 2) ? d2 : d3;
    float inv = 1.f / dh;
    acc0 *= inv; acc1 *= inv; acc2 *= inv; acc3 *= inv;
  }
  float4 o4 = { acc0, acc1, acc2, acc3 };
  *reinterpret_cast<float4*>(out + (size_t)n * OUT_C + 4 * lane) = o4;
}

extern "C" void kernel_launch(void* const* d_in, const int* in_sizes, int n_in,
                              void* d_out, int out_size, void* d_ws, size_t ws_size,
                              hipStream_t stream) {
  const float* hmat  = (const float*)d_in[0];
  const int*   src   = (const int*)d_in[1];
  const int*   dst   = (const int*)d_in[2];
  const float* Wmat  = (const float*)d_in[3];
  const float* avsrc = (const float*)d_in[4];
  const float* avdst = (const float*)d_in[5];
  float* out = (float*)d_out;
  const int N = in_sizes[0] / IN_DIM;
  const int E = in_sizes[1];
  const int NB = (N + SCAN_CHUNK - 1) / SCAN_CHUNK;   // 25 for N=50000

  char* ws = (char*)d_ws;
  size_t off = 0;
  auto alloc = [&](size_t bytes) -> void* {
    void* p = ws + off;
    off = (off + bytes + 255) & ~(size_t)255;
    return p;
  };
  ushort* hb      = (ushort*)alloc((size_t)N * IN_DIM * sizeof(ushort));     // 25.6 MB
  ushort* BT      = (ushort*)alloc((size_t)OUT_C * IN_DIM * sizeof(ushort)); // 128 KB
  ushort* zb      = (ushort*)alloc((size_t)N * OUT_C * sizeof(ushort));      // 25.6 MB
  float*  es      = (float*)alloc((size_t)N * NHEADS * sizeof(float));
  float*  ed      = (float*)alloc((size_t)N * NHEADS * sizeof(float));
  float*  eVal    = (float*)alloc((size_t)E * NHEADS * sizeof(float));       // 12.8 MB
  int*    counts  = (int*)alloc((size_t)N * sizeof(int));
  int*    offsets = (int*)alloc((size_t)(N + 1) * sizeof(int));
  int*    cursor  = (int*)alloc((size_t)N * sizeof(int));
  int*    edge_idx= (int*)alloc((size_t)E * sizeof(int));                    // 3.2 MB
  int*    partials= (int*)alloc((size_t)256 * sizeof(int));

  hipLaunchKernelGGL(k_zero, dim3((N + 255) / 256), dim3(256), 0, stream, counts, N);
  hipLaunchKernelGGL(k_cast_h, dim3(2048), dim3(256), 0, stream,
                     hmat, hb, N * IN_DIM / 4);
  hipLaunchKernelGGL(k_prep_w, dim3(256), dim3(256), 0, stream, Wmat, BT);
  hipLaunchKernelGGL(k_gemm_mfma, dim3((N + 63) / 64), dim3(256), 0, stream,
                     hb, BT, avsrc, avdst, zb, es, ed, N);
  hipLaunchKernelGGL(k_edge, dim3((E + 255) / 256), dim3(256), 0, stream,
                     src, dst, es, ed, eVal, counts, E);
  hipLaunchKernelGGL(k_scan_part, dim3(NB), dim3(256), 0, stream, counts, partials, N);
  hipLaunchKernelGGL(k_scan_top, dim3(1), dim3(256), 0, stream, partials, NB);
  hipLaunchKernelGGL(k_scan_final, dim3(NB), dim3(256), 0, stream,
                     counts, partials, offsets, cursor, N);
  hipLaunchKernelGGL(k_scatter, dim3((E + 255) / 256), dim3(256), 0, stream,
                     dst, cursor, edge_idx, E);
  hipLaunchKernelGGL(k_aggregate, dim3(N), dim3(64), 0, stream,
                     offsets, edge_idx, src, eVal, zb, out, N);
}

// Round 5
// 220.843 us; speedup vs baseline: 2.2138x; 1.0754x over previous
//
#include <hip/hip_runtime.h>
#include <math.h>

#define IN_DIM  256
#define OUT_C   256   // N_HEADS * OUT_DIM
#define NHEADS  4
#define SCAN_CHUNK 2048

typedef __attribute__((ext_vector_type(8))) short short8;
typedef __attribute__((ext_vector_type(4))) float f32x4;

static __device__ __forceinline__ float lrelu(float x) { return x > 0.f ? x : 0.01f * x; }

// round-to-nearest-even f32 -> bf16 bits
static __device__ __forceinline__ uint f2bf(float f) {
  uint u = __float_as_uint(f);
  return (u + 0x7fffu + ((u >> 16) & 1u)) >> 16;
}
static __device__ __forceinline__ float bflo(uint v) { return __uint_as_float(v << 16); }
static __device__ __forceinline__ float bfhi(uint v) { return __uint_as_float(v & 0xffff0000u); }

// ---------------- zero int buffer ----------------
__global__ void k_zero(int* __restrict__ p, int n) {
  int i = blockIdx.x * blockDim.x + threadIdx.x;
  if (i < n) p[i] = 0;
}

// ---------------- W [4][256][64] f32 -> BT [256 cols][256 k] bf16 ----------------
__global__ __launch_bounds__(256) void k_prep_w(const float* __restrict__ W,
                                                ushort* __restrict__ BT) {
  int t = blockIdx.x * 256 + threadIdx.x;          // 65536 total
  int hh = t >> 14, k = (t >> 6) & 255, o = t & 63;
  BT[(hh * 64 + o) * 256 + k] = (ushort)f2bf(W[t]);
}

// ---------------- MFMA GEMM: zb = bf16( bf16(h) @ B ), fused cast + e_src/e_dst -
// tile 64 rows x 256 cols, 4 waves; wave w owns cols [w*64, w*64+64).
__global__ __launch_bounds__(256) void k_gemm_mfma(const float* __restrict__ hmat,
                                                   const ushort* __restrict__ BT,
                                                   const float* __restrict__ avsrc,
                                                   const float* __restrict__ avdst,
                                                   ushort* __restrict__ zb,
                                                   float* __restrict__ es,
                                                   float* __restrict__ ed, int N) {
  __shared__ ushort sA[64 * 32];    // [row][k]  4 KB
  __shared__ ushort sB[256 * 32];   // [col][k] 16 KB
  const int tid = threadIdx.x;
  const int w   = tid >> 6;
  const int l   = tid & 63;
  const int n0  = blockIdx.x * 64;
  const int l15 = l & 15;
  const int lg  = l >> 4;           // 16-lane group id
  f32x4 acc[4][4] = {};

  for (int k0 = 0; k0 < IN_DIM; k0 += 32) {
    // stage A: 64x32, f32 load + in-register bf16 pack (fused cast)
    {
      int row = tid >> 2, ko = (tid & 3) * 8;
      int gr = n0 + row; if (gr >= N) gr = N - 1;
      const float* hp = hmat + (size_t)gr * IN_DIM + k0 + ko;
      float4 f0 = *reinterpret_cast<const float4*>(hp);
      float4 f1 = *reinterpret_cast<const float4*>(hp + 4);
      uint4 o;
      o.x = f2bf(f0.x) | (f2bf(f0.y) << 16);
      o.y = f2bf(f0.z) | (f2bf(f0.w) << 16);
      o.z = f2bf(f1.x) | (f2bf(f1.y) << 16);
      o.w = f2bf(f1.z) | (f2bf(f1.w) << 16);
      *reinterpret_cast<uint4*>(sA + row * 32 + ko) = o;
    }
    // stage B: 256x32 bf16 = 16KB, 4 uint4 per thread
    #pragma unroll
    for (int q = 0; q < 4; ++q) {
      int fid = q * 256 + tid;
      int col = fid >> 2, ko = (fid & 3) * 8;
      uint4 v = *reinterpret_cast<const uint4*>(BT + (size_t)col * 256 + k0 + ko);
      *reinterpret_cast<uint4*>(sB + col * 32 + ko) = v;
    }
    __syncthreads();
    const int ksel = lg * 8;
    short8 a[4], b[4];
    #pragma unroll
    for (int m = 0; m < 4; ++m)
      a[m] = *reinterpret_cast<const short8*>(sA + (m * 16 + l15) * 32 + ksel);
    #pragma unroll
    for (int cf = 0; cf < 4; ++cf)
      b[cf] = *reinterpret_cast<const short8*>(sB + (w * 64 + cf * 16 + l15) * 32 + ksel);
    #pragma unroll
    for (int m = 0; m < 4; ++m)
      #pragma unroll
      for (int cf = 0; cf < 4; ++cf)
        acc[m][cf] = __builtin_amdgcn_mfma_f32_16x16x32_bf16(a[m], b[cf], acc[m][cf], 0, 0, 0);
    __syncthreads();
  }

  // epilogue: z store (bf16) + fused e_src/e_dst
  float asv[4], adv[4];
  #pragma unroll
  for (int cf = 0; cf < 4; ++cf) {
    asv[cf] = avsrc[w * 64 + cf * 16 + l15];
    adv[cf] = avdst[w * 64 + cf * 16 + l15];
  }
  #pragma unroll
  for (int m = 0; m < 4; ++m) {
    #pragma unroll
    for (int r = 0; r < 4; ++r) {
      int row = m * 16 + lg * 4 + r;
      int gr  = n0 + row;
      float ss = 0.f, dd = 0.f;
      #pragma unroll
      for (int cf = 0; cf < 4; ++cf) {
        ss = fmaf(acc[m][cf][r], asv[cf], ss);
        dd = fmaf(acc[m][cf][r], adv[cf], dd);
      }
      #pragma unroll
      for (int s = 1; s < 16; s <<= 1) {
        ss += __shfl_xor(ss, s);
        dd += __shfl_xor(dd, s);
      }
      if (gr < N) {
        if (l15 == 0) { es[gr * 4 + w] = ss; ed[gr * 4 + w] = dd; }
        #pragma unroll
        for (int cf = 0; cf < 4; ++cf)
          zb[(size_t)gr * OUT_C + w * 64 + cf * 16 + l15] = (ushort)f2bf(acc[m][cf][r]);
      }
    }
  }
}

// ---------------- degree counts ----------------
__global__ void k_count(const int* __restrict__ dst, int* __restrict__ counts, int E) {
  int e = blockIdx.x * blockDim.x + threadIdx.x;
  if (e < E) atomicAdd(&counts[dst[e]], 1);
}

// ---------------- hierarchical scan, phase 1: per-block chunk sums ----------------
__global__ __launch_bounds__(256) void k_scan_part(const int* __restrict__ counts,
                                                   int* __restrict__ partials, int N) {
  __shared__ int ssum[256];
  int tid  = threadIdx.x;
  int idx  = blockIdx.x * SCAN_CHUNK + tid * 8;
  int s = 0;
  #pragma unroll
  for (int j = 0; j < 8; ++j) {
    int i = idx + j;
    if (i < N) s += counts[i];
  }
  ssum[tid] = s;
  __syncthreads();
  #pragma unroll
  for (int off = 128; off > 0; off >>= 1) {
    if (tid < off) ssum[tid] += ssum[tid + off];
    __syncthreads();
  }
  if (tid == 0) partials[blockIdx.x] = ssum[0];
}

// ---------------- phase 2: exclusive scan of partials (single block) ----------------
__global__ __launch_bounds__(256) void k_scan_top(int* __restrict__ partials, int B) {
  __shared__ int t[256];
  int tid  = threadIdx.x;
  int orig = (tid < B) ? partials[tid] : 0;
  t[tid] = orig;
  __syncthreads();
  #pragma unroll
  for (int off = 1; off < 256; off <<= 1) {
    int v = (tid >= off) ? t[tid - off] : 0;
    __syncthreads();
    t[tid] += v;
    __syncthreads();
  }
  if (tid < B) partials[tid] = t[tid] - orig;   // exclusive
}

// ---------------- phase 3: final scan: offsets + cursor ----------------
__global__ __launch_bounds__(256) void k_scan_final(const int* __restrict__ counts,
                                                    const int* __restrict__ partials,
                                                    int* __restrict__ offsets,
                                                    int* __restrict__ cursor, int N) {
  __shared__ int tsum[256];
  int tid = threadIdx.x;
  int idx = blockIdx.x * SCAN_CHUNK + tid * 8;
  int local[8];
  int s = 0;
  #pragma unroll
  for (int j = 0; j < 8; ++j) {
    int i = idx + j;
    local[j] = (i < N) ? counts[i] : 0;
    s += local[j];
  }
  tsum[tid] = s;
  __syncthreads();
  #pragma unroll
  for (int off = 1; off < 256; off <<= 1) {
    int v = (tid >= off) ? tsum[tid - off] : 0;
    __syncthreads();
    tsum[tid] += v;
    __syncthreads();
  }
  int run = tsum[tid] - s + partials[blockIdx.x];
  #pragma unroll
  for (int j = 0; j < 8; ++j) {
    int i = idx + j;
    if (i < N) {
      offsets[i] = run;
      cursor[i]  = run;
      run += local[j];
      if (i == N - 1) offsets[N] = run;
    }
  }
}

// ---------------- fused edge kernel: p = exp(lrelu(es+ed)), scatter into CSR ----
__global__ void k_scatter_p(const int* __restrict__ src, const int* __restrict__ dst,
                            const float* __restrict__ es, const float* __restrict__ ed,
                            int* __restrict__ cursor,
                            float4* __restrict__ pE, int* __restrict__ sE, int E) {
  int e = blockIdx.x * blockDim.x + threadIdx.x;
  if (e >= E) return;
  int s = src[e], d = dst[e];
  float4 a = *reinterpret_cast<const float4*>(&es[4 * s]);
  float4 b = *reinterpret_cast<const float4*>(&ed[4 * d]);
  float4 p;
  p.x = __expf(lrelu(a.x + b.x));
  p.y = __expf(lrelu(a.y + b.y));
  p.z = __expf(lrelu(a.z + b.z));
  p.w = __expf(lrelu(a.w + b.w));
  int pos = atomicAdd(&cursor[d], 1);
  pE[pos] = p;
  sE[pos] = s;
}

// ---------------- aggregation: 4 waves/block, 1 node/wave, no LDS/barriers -----
// lane = 16*g + l15; group g owns head g, channels [64g+4*l15, +4).
// Edge index i is wave-uniform -> sE[i] scalarizes; p is a coalesced 16B load.
__global__ __launch_bounds__(256, 8) void k_aggregate(const int* __restrict__ offsets,
                                                      const float* __restrict__ pE,
                                                      const int* __restrict__ sE,
                                                      const ushort* __restrict__ zb,
                                                      float* __restrict__ out, int N) {
  int n = blockIdx.x * 4 + (threadIdx.x >> 6);
  if (n >= N) return;
  int lane = threadIdx.x & 63;
  int g    = lane >> 4;
  int beg  = offsets[n], end = offsets[n + 1];

  float acc0 = 0.f, acc1 = 0.f, acc2 = 0.f, acc3 = 0.f, denom = 0.f;
  for (int i = beg; i < end; ++i) {
    int   s = sE[i];                       // uniform across wave
    float p = pE[4 * i + g];               // 16B coalesced across wave
    uint2 v = reinterpret_cast<const uint2*>(zb + (size_t)s * OUT_C)[lane];
    denom += p;
    acc0 = fmaf(p, bflo(v.x), acc0);
    acc1 = fmaf(p, bfhi(v.x), acc1);
    acc2 = fmaf(p, bflo(v.y), acc2);
    acc3 = fmaf(p, bfhi(v.y), acc3);
  }
  if (end > beg) {
    float inv = 1.f / denom;
    acc0 *= inv; acc1 *= inv; acc2 *= inv; acc3 *= inv;
  }
  float4 o4 = { acc0, acc1, acc2, acc3 };
  *reinterpret_cast<float4*>(out + (size_t)n * OUT_C + 4 * lane) = o4;
}

extern "C" void kernel_launch(void* const* d_in, const int* in_sizes, int n_in,
                              void* d_out, int out_size, void* d_ws, size_t ws_size,
                              hipStream_t stream) {
  const float* hmat  = (const float*)d_in[0];
  const int*   src   = (const int*)d_in[1];
  const int*   dst   = (const int*)d_in[2];
  const float* Wmat  = (const float*)d_in[3];
  const float* avsrc = (const float*)d_in[4];
  const float* avdst = (const float*)d_in[5];
  float* out = (float*)d_out;
  const int N = in_sizes[0] / IN_DIM;
  const int E = in_sizes[1];
  const int NB = (N + SCAN_CHUNK - 1) / SCAN_CHUNK;   // 25 for N=50000

  char* ws = (char*)d_ws;
  size_t off = 0;
  auto alloc = [&](size_t bytes) -> void* {
    void* p = ws + off;
    off = (off + bytes + 255) & ~(size_t)255;
    return p;
  };
  ushort* BT      = (ushort*)alloc((size_t)OUT_C * IN_DIM * sizeof(ushort)); // 128 KB
  ushort* zb      = (ushort*)alloc((size_t)N * OUT_C * sizeof(ushort));      // 25.6 MB
  float*  es      = (float*)alloc((size_t)N * NHEADS * sizeof(float));
  float*  ed      = (float*)alloc((size_t)N * NHEADS * sizeof(float));
  int*    counts  = (int*)alloc((size_t)N * sizeof(int));
  int*    offsets = (int*)alloc((size_t)(N + 1) * sizeof(int));
  int*    cursor  = (int*)alloc((size_t)N * sizeof(int));
  float4* pE      = (float4*)alloc((size_t)E * sizeof(float4));              // 12.8 MB
  int*    sE      = (int*)alloc((size_t)E * sizeof(int));                    // 3.2 MB
  int*    partials= (int*)alloc((size_t)256 * sizeof(int));

  hipLaunchKernelGGL(k_zero, dim3((N + 255) / 256), dim3(256), 0, stream, counts, N);
  hipLaunchKernelGGL(k_prep_w, dim3(256), dim3(256), 0, stream, Wmat, BT);
  hipLaunchKernelGGL(k_gemm_mfma, dim3((N + 63) / 64), dim3(256), 0, stream,
                     hmat, BT, avsrc, avdst, zb, es, ed, N);
  hipLaunchKernelGGL(k_count, dim3((E + 255) / 256), dim3(256), 0, stream,
                     dst, counts, E);
  hipLaunchKernelGGL(k_scan_part, dim3(NB), dim3(256), 0, stream, counts, partials, N);
  hipLaunchKernelGGL(k_scan_top, dim3(1), dim3(256), 0, stream, partials, NB);
  hipLaunchKernelGGL(k_scan_final, dim3(NB), dim3(256), 0, stream,
                     counts, partials, offsets, cursor, N);
  hipLaunchKernelGGL(k_scatter_p, dim3((E + 255) / 256), dim3(256), 0, stream,
                     src, dst, es, ed, cursor, pE, sE, E);
  hipLaunchKernelGGL(k_aggregate, dim3((N + 3) / 4), dim3(256), 0, stream,
                     offsets, (const float*)pE, sE, zb, out, N);
}

// Round 6
// 192.987 us; speedup vs baseline: 2.5333x; 1.1443x over previous
//
#include <hip/hip_runtime.h>
#include <math.h>

#define IN_DIM  256
#define OUT_C   256   // N_HEADS * OUT_DIM
#define NHEADS  4
#define SCAN_CHUNK 2048

typedef __attribute__((ext_vector_type(8))) short short8;
typedef __attribute__((ext_vector_type(4))) float f32x4;

static __device__ __forceinline__ float lrelu(float x) { return x > 0.f ? x : 0.01f * x; }

// round-to-nearest-even f32 -> bf16 bits
static __device__ __forceinline__ uint f2bf(float f) {
  uint u = __float_as_uint(f);
  return (u + 0x7fffu + ((u >> 16) & 1u)) >> 16;
}
static __device__ __forceinline__ float bflo(uint v) { return __uint_as_float(v << 16); }
static __device__ __forceinline__ float bfhi(uint v) { return __uint_as_float(v & 0xffff0000u); }

// ---------------- zero int buffer ----------------
__global__ void k_zero(int* __restrict__ p, int n) {
  int i = blockIdx.x * blockDim.x + threadIdx.x;
  if (i < n) p[i] = 0;
}

// ---------------- W [4][256][64] f32 -> BT [256 cols][256 k] bf16 ----------------
__global__ __launch_bounds__(256) void k_prep_w(const float* __restrict__ W,
                                                ushort* __restrict__ BT) {
  int t = blockIdx.x * 256 + threadIdx.x;          // 65536 total
  int hh = t >> 14, k = (t >> 6) & 255, o = t & 63;
  BT[(hh * 64 + o) * 256 + k] = (ushort)f2bf(W[t]);
}

// ---------------- MFMA GEMM: zb = bf16( bf16(h) @ B ), fused cast + e_src/e_dst -
__global__ __launch_bounds__(256) void k_gemm_mfma(const float* __restrict__ hmat,
                                                   const ushort* __restrict__ BT,
                                                   const float* __restrict__ avsrc,
                                                   const float* __restrict__ avdst,
                                                   ushort* __restrict__ zb,
                                                   float* __restrict__ es,
                                                   float* __restrict__ ed, int N) {
  __shared__ ushort sA[64 * 32];    // [row][k]  4 KB
  __shared__ ushort sB[256 * 32];   // [col][k] 16 KB
  const int tid = threadIdx.x;
  const int w   = tid >> 6;
  const int l   = tid & 63;
  const int n0  = blockIdx.x * 64;
  const int l15 = l & 15;
  const int lg  = l >> 4;           // 16-lane group id
  f32x4 acc[4][4] = {};

  for (int k0 = 0; k0 < IN_DIM; k0 += 32) {
    // stage A: 64x32, f32 load + in-register bf16 pack (fused cast)
    {
      int row = tid >> 2, ko = (tid & 3) * 8;
      int gr = n0 + row; if (gr >= N) gr = N - 1;
      const float* hp = hmat + (size_t)gr * IN_DIM + k0 + ko;
      float4 f0 = *reinterpret_cast<const float4*>(hp);
      float4 f1 = *reinterpret_cast<const float4*>(hp + 4);
      uint4 o;
      o.x = f2bf(f0.x) | (f2bf(f0.y) << 16);
      o.y = f2bf(f0.z) | (f2bf(f0.w) << 16);
      o.z = f2bf(f1.x) | (f2bf(f1.y) << 16);
      o.w = f2bf(f1.z) | (f2bf(f1.w) << 16);
      *reinterpret_cast<uint4*>(sA + row * 32 + ko) = o;
    }
    // stage B: 256x32 bf16 = 16KB, 4 uint4 per thread
    #pragma unroll
    for (int q = 0; q < 4; ++q) {
      int fid = q * 256 + tid;
      int col = fid >> 2, ko = (fid & 3) * 8;
      uint4 v = *reinterpret_cast<const uint4*>(BT + (size_t)col * 256 + k0 + ko);
      *reinterpret_cast<uint4*>(sB + col * 32 + ko) = v;
    }
    __syncthreads();
    const int ksel = lg * 8;
    short8 a[4], b[4];
    #pragma unroll
    for (int m = 0; m < 4; ++m)
      a[m] = *reinterpret_cast<const short8*>(sA + (m * 16 + l15) * 32 + ksel);
    #pragma unroll
    for (int cf = 0; cf < 4; ++cf)
      b[cf] = *reinterpret_cast<const short8*>(sB + (w * 64 + cf * 16 + l15) * 32 + ksel);
    #pragma unroll
    for (int m = 0; m < 4; ++m)
      #pragma unroll
      for (int cf = 0; cf < 4; ++cf)
        acc[m][cf] = __builtin_amdgcn_mfma_f32_16x16x32_bf16(a[m], b[cf], acc[m][cf], 0, 0, 0);
    __syncthreads();
  }

  // epilogue: z store (bf16) + fused e_src/e_dst
  float asv[4], adv[4];
  #pragma unroll
  for (int cf = 0; cf < 4; ++cf) {
    asv[cf] = avsrc[w * 64 + cf * 16 + l15];
    adv[cf] = avdst[w * 64 + cf * 16 + l15];
  }
  #pragma unroll
  for (int m = 0; m < 4; ++m) {
    #pragma unroll
    for (int r = 0; r < 4; ++r) {
      int row = m * 16 + lg * 4 + r;
      int gr  = n0 + row;
      float ss = 0.f, dd = 0.f;
      #pragma unroll
      for (int cf = 0; cf < 4; ++cf) {
        ss = fmaf(acc[m][cf][r], asv[cf], ss);
        dd = fmaf(acc[m][cf][r], adv[cf], dd);
      }
      #pragma unroll
      for (int s = 1; s < 16; s <<= 1) {
        ss += __shfl_xor(ss, s);
        dd += __shfl_xor(dd, s);
      }
      if (gr < N) {
        if (l15 == 0) { es[gr * 4 + w] = ss; ed[gr * 4 + w] = dd; }
        #pragma unroll
        for (int cf = 0; cf < 4; ++cf)
          zb[(size_t)gr * OUT_C + w * 64 + cf * 16 + l15] = (ushort)f2bf(acc[m][cf][r]);
      }
    }
  }
}

// ---------------- degree counts ----------------
__global__ void k_count(const int* __restrict__ dst, int* __restrict__ counts, int E) {
  int e = blockIdx.x * blockDim.x + threadIdx.x;
  if (e < E) atomicAdd(&counts[dst[e]], 1);
}

// ---------------- hierarchical scan over PADDED counts ----------------
__global__ __launch_bounds__(256) void k_scan_part(const int* __restrict__ counts,
                                                   int* __restrict__ partials, int N) {
  __shared__ int ssum[256];
  int tid  = threadIdx.x;
  int idx  = blockIdx.x * SCAN_CHUNK + tid * 8;
  int s = 0;
  #pragma unroll
  for (int j = 0; j < 8; ++j) {
    int i = idx + j;
    if (i < N) s += (counts[i] + 3) & ~3;
  }
  ssum[tid] = s;
  __syncthreads();
  #pragma unroll
  for (int off = 128; off > 0; off >>= 1) {
    if (tid < off) ssum[tid] += ssum[tid + off];
    __syncthreads();
  }
  if (tid == 0) partials[blockIdx.x] = ssum[0];
}

__global__ __launch_bounds__(256) void k_scan_top(int* __restrict__ partials, int B) {
  __shared__ int t[256];
  int tid  = threadIdx.x;
  int orig = (tid < B) ? partials[tid] : 0;
  t[tid] = orig;
  __syncthreads();
  #pragma unroll
  for (int off = 1; off < 256; off <<= 1) {
    int v = (tid >= off) ? t[tid - off] : 0;
    __syncthreads();
    t[tid] += v;
    __syncthreads();
  }
  if (tid < B) partials[tid] = t[tid] - orig;   // exclusive
}

__global__ __launch_bounds__(256) void k_scan_final(const int* __restrict__ counts,
                                                    const int* __restrict__ partials,
                                                    int* __restrict__ offsets,
                                                    int* __restrict__ cursor, int N) {
  __shared__ int tsum[256];
  int tid = threadIdx.x;
  int idx = blockIdx.x * SCAN_CHUNK + tid * 8;
  int local[8];
  int s = 0;
  #pragma unroll
  for (int j = 0; j < 8; ++j) {
    int i = idx + j;
    local[j] = (i < N) ? ((counts[i] + 3) & ~3) : 0;
    s += local[j];
  }
  tsum[tid] = s;
  __syncthreads();
  #pragma unroll
  for (int off = 1; off < 256; off <<= 1) {
    int v = (tid >= off) ? tsum[tid - off] : 0;
    __syncthreads();
    tsum[tid] += v;
    __syncthreads();
  }
  int run = tsum[tid] - s + partials[blockIdx.x];
  #pragma unroll
  for (int j = 0; j < 8; ++j) {
    int i = idx + j;
    if (i < N) {
      offsets[i] = run;
      cursor[i]  = run;
      run += local[j];
      if (i == N - 1) offsets[N] = run;
    }
  }
}

// ---------------- zero-fill padded dummy slots ----------------
__global__ void k_pad(const int* __restrict__ counts, const int* __restrict__ offsets,
                      float4* __restrict__ pE, int* __restrict__ sE, int N) {
  int i = blockIdx.x * blockDim.x + threadIdx.x;
  if (i >= N) return;
  int b = offsets[i] + counts[i];
  int e = offsets[i + 1];
  for (int j = b; j < e; ++j) {
    pE[j] = float4{0.f, 0.f, 0.f, 0.f};
    sE[j] = 0;
  }
}

// ---------------- fused edge kernel: p = exp(lrelu(es+ed)), scatter into CSR ----
__global__ void k_scatter_p(const int* __restrict__ src, const int* __restrict__ dst,
                            const float* __restrict__ es, const float* __restrict__ ed,
                            int* __restrict__ cursor,
                            float4* __restrict__ pE, int* __restrict__ sE, int E) {
  int e = blockIdx.x * blockDim.x + threadIdx.x;
  if (e >= E) return;
  int s = src[e], d = dst[e];
  float4 a = *reinterpret_cast<const float4*>(&es[4 * s]);
  float4 b = *reinterpret_cast<const float4*>(&ed[4 * d]);
  float4 p;
  p.x = __expf(lrelu(a.x + b.x));
  p.y = __expf(lrelu(a.y + b.y));
  p.z = __expf(lrelu(a.z + b.z));
  p.w = __expf(lrelu(a.w + b.w));
  int pos = atomicAdd(&cursor[d], 1);
  pE[pos] = p;
  sE[pos] = s;
}

// ---------------- aggregation: 4 waves/block, 1 node/wave, 4-edge batches -------
// Segments are padded to multiples of 4 and 16B-aligned; dummy slots have p=0.
// Per iteration: 1 int4 sE load + 4 scalar p loads + 4 independent 512B z-gathers.
__global__ __launch_bounds__(256, 8) void k_aggregate(const int* __restrict__ offsets,
                                                      const float* __restrict__ pEf,
                                                      const int* __restrict__ sE,
                                                      const ushort* __restrict__ zb,
                                                      float* __restrict__ out, int N) {
  int n = blockIdx.x * 4 + (threadIdx.x >> 6);
  if (n >= N) return;
  int lane = threadIdx.x & 63;
  int g    = lane >> 4;
  int beg  = offsets[n], end = offsets[n + 1];

  float acc0 = 0.f, acc1 = 0.f, acc2 = 0.f, acc3 = 0.f, denom = 0.f;
  for (int i = beg; i < end; i += 4) {
    int4 s4 = *reinterpret_cast<const int4*>(sE + i);
    float p0 = pEf[4 * i + g];
    float p1 = pEf[4 * i + 4 + g];
    float p2 = pEf[4 * i + 8 + g];
    float p3 = pEf[4 * i + 12 + g];
    uint2 v0 = reinterpret_cast<const uint2*>(zb + (size_t)s4.x * OUT_C)[lane];
    uint2 v1 = reinterpret_cast<const uint2*>(zb + (size_t)s4.y * OUT_C)[lane];
    uint2 v2 = reinterpret_cast<const uint2*>(zb + (size_t)s4.z * OUT_C)[lane];
    uint2 v3 = reinterpret_cast<const uint2*>(zb + (size_t)s4.w * OUT_C)[lane];
    denom += (p0 + p1) + (p2 + p3);
    acc0 = fmaf(p0, bflo(v0.x), acc0);
    acc1 = fmaf(p0, bfhi(v0.x), acc1);
    acc2 = fmaf(p0, bflo(v0.y), acc2);
    acc3 = fmaf(p0, bfhi(v0.y), acc3);
    acc0 = fmaf(p1, bflo(v1.x), acc0);
    acc1 = fmaf(p1, bfhi(v1.x), acc1);
    acc2 = fmaf(p1, bflo(v1.y), acc2);
    acc3 = fmaf(p1, bfhi(v1.y), acc3);
    acc0 = fmaf(p2, bflo(v2.x), acc0);
    acc1 = fmaf(p2, bfhi(v2.x), acc1);
    acc2 = fmaf(p2, bflo(v2.y), acc2);
    acc3 = fmaf(p2, bfhi(v2.y), acc3);
    acc0 = fmaf(p3, bflo(v3.x), acc0);
    acc1 = fmaf(p3, bfhi(v3.x), acc1);
    acc2 = fmaf(p3, bflo(v3.y), acc2);
    acc3 = fmaf(p3, bfhi(v3.y), acc3);
  }
  if (end > beg) {
    float inv = 1.f / denom;
    acc0 *= inv; acc1 *= inv; acc2 *= inv; acc3 *= inv;
  }
  float4 o4 = { acc0, acc1, acc2, acc3 };
  *reinterpret_cast<float4*>(out + (size_t)n * OUT_C + 4 * lane) = o4;
}

extern "C" void kernel_launch(void* const* d_in, const int* in_sizes, int n_in,
                              void* d_out, int out_size, void* d_ws, size_t ws_size,
                              hipStream_t stream) {
  const float* hmat  = (const float*)d_in[0];
  const int*   src   = (const int*)d_in[1];
  const int*   dst   = (const int*)d_in[2];
  const float* Wmat  = (const float*)d_in[3];
  const float* avsrc = (const float*)d_in[4];
  const float* avdst = (const float*)d_in[5];
  float* out = (float*)d_out;
  const int N = in_sizes[0] / IN_DIM;
  const int E = in_sizes[1];
  const int NB = (N + SCAN_CHUNK - 1) / SCAN_CHUNK;   // 25 for N=50000
  const size_t EP = (size_t)E + 4 * (size_t)N + 16;   // padded edge capacity

  char* ws = (char*)d_ws;
  size_t off = 0;
  auto alloc = [&](size_t bytes) -> void* {
    void* p = ws + off;
    off = (off + bytes + 255) & ~(size_t)255;
    return p;
  };
  ushort* BT      = (ushort*)alloc((size_t)OUT_C * IN_DIM * sizeof(ushort)); // 128 KB
  ushort* zb      = (ushort*)alloc((size_t)N * OUT_C * sizeof(ushort));      // 25.6 MB
  float*  es      = (float*)alloc((size_t)N * NHEADS * sizeof(float));
  float*  ed      = (float*)alloc((size_t)N * NHEADS * sizeof(float));
  int*    counts  = (int*)alloc((size_t)N * sizeof(int));
  int*    offsets = (int*)alloc((size_t)(N + 1) * sizeof(int));
  int*    cursor  = (int*)alloc((size_t)N * sizeof(int));
  float4* pE      = (float4*)alloc(EP * sizeof(float4));                     // ~15.5 MB
  int*    sE      = (int*)alloc(EP * sizeof(int));                           // ~3.9 MB
  int*    partials= (int*)alloc((size_t)256 * sizeof(int));

  hipLaunchKernelGGL(k_zero, dim3((N + 255) / 256), dim3(256), 0, stream, counts, N);
  hipLaunchKernelGGL(k_prep_w, dim3(256), dim3(256), 0, stream, Wmat, BT);
  hipLaunchKernelGGL(k_gemm_mfma, dim3((N + 63) / 64), dim3(256), 0, stream,
                     hmat, BT, avsrc, avdst, zb, es, ed, N);
  hipLaunchKernelGGL(k_count, dim3((E + 255) / 256), dim3(256), 0, stream,
                     dst, counts, E);
  hipLaunchKernelGGL(k_scan_part, dim3(NB), dim3(256), 0, stream, counts, partials, N);
  hipLaunchKernelGGL(k_scan_top, dim3(1), dim3(256), 0, stream, partials, NB);
  hipLaunchKernelGGL(k_scan_final, dim3(NB), dim3(256), 0, stream,
                     counts, partials, offsets, cursor, N);
  hipLaunchKernelGGL(k_pad, dim3((N + 255) / 256), dim3(256), 0, stream,
                     counts, offsets, pE, sE, N);
  hipLaunchKernelGGL(k_scatter_p, dim3((E + 255) / 256), dim3(256), 0, stream,
                     src, dst, es, ed, cursor, pE, sE, E);
  hipLaunchKernelGGL(k_aggregate, dim3((N + 3) / 4), dim3(256), 0, stream,
                     offsets, (const float*)pE, sE, zb, out, N);
}